// Round 5
// baseline (243.924 us; speedup 1.0000x reference)
//
#include <hip/hip_runtime.h>
#include <hip/hip_bf16.h>
#include <math.h>

#define BB 1024     // batch
#define LL 50       // sequence length
#define DD 256      // embedding dim
#define TWO_D 512
#define NN 40000    // nodes
#define DEG 12      // neighbors per node (adj_rows = repeat(arange(N), DEG))
#define NITER 50    // entmax bisect iterations

typedef __attribute__((ext_vector_type(8))) short short8;
typedef __attribute__((ext_vector_type(4))) float floatx4;

__device__ __forceinline__ float wave_sum64(float v) {
#pragma unroll
    for (int off = 32; off > 0; off >>= 1) v += __shfl_xor(v, off, 64);
    return v;
}
__device__ __forceinline__ float wave_max64(float v) {
#pragma unroll
    for (int off = 32; off > 0; off >>= 1) v = fmaxf(v, __shfl_xor(v, off, 64));
    return v;
}
// Full-wave sum via DPP (canonical GCN sequence), result uniform via readlane.
__device__ __forceinline__ float dpp_sum64(float v) {
#define DPPADD(ctrl, rm, bm) \
    v += __int_as_float(__builtin_amdgcn_update_dpp(0, __float_as_int(v), ctrl, rm, bm, true))
    DPPADD(0x111, 0xF, 0xF);   // row_shr:1
    DPPADD(0x112, 0xF, 0xF);   // row_shr:2
    DPPADD(0x114, 0xF, 0xE);   // row_shr:4
    DPPADD(0x118, 0xF, 0xC);   // row_shr:8
    DPPADD(0x142, 0xA, 0xF);   // row_bcast:15
    DPPADD(0x143, 0xC, 0xF);   // row_bcast:31  -> lane63 = full sum
#undef DPPADD
    return __int_as_float(__builtin_amdgcn_readlane(__float_as_int(v), 63));
}
__device__ __forceinline__ float bf2f(ushort u) {
    union { unsigned int i; float f; } c; c.i = ((unsigned int)u) << 16; return c.f;
}
__device__ __forceinline__ ushort f2bf(float f) {
    __hip_bfloat16 h = __float2bfloat16(f);
    return *(ushort*)&h;
}
__device__ __forceinline__ float hw_exp2(float x) { return __builtin_amdgcn_exp2f(x); }
__device__ __forceinline__ float hw_log2(float x) { return __builtin_amdgcn_logf(x); }

// ---------------- L1: wprep (blocked GEMM) | w1t | bc/c0 | mark | emb->bf16 -
// bid [0,32):   Wc[k0:k0+16][:] = wf_w[:,k0:k0+16]^T @ at_w2 — each block
//               streams at_w2 ONCE (256 KB); logical traffic 32*256KB = 8 MB
//               (was 512 blocks * 256KB = 128 MB). v[k] folded in.
// bid [32,96):  w1t transpose, 4 cols per block (old proven path).
// bid 96:       bc[n] = at_bias[n] + wf_b @ at_w2[:,n]; c0 = wf_b@aw + ab.
// bid [97,297): flags[items[i]] = 1
// bid [297,1547): ebf = bf16(item_emb), 8 independent float4 per thread
__global__ __launch_bounds__(256) void k_stage1(
    const float* __restrict__ emb, ushort* __restrict__ ebf,
    const int* __restrict__ items, int* __restrict__ flags,
    const float* __restrict__ wf_w, const float* __restrict__ wf_b,
    const float* __restrict__ at_w2, const float* __restrict__ at_bias,
    const float* __restrict__ aw, const float* __restrict__ ab,
    const float* __restrict__ at_w1,
    float* __restrict__ Wc, float* __restrict__ v,
    float* __restrict__ bc, float* __restrict__ c0,
    ushort* __restrict__ w1t)
{
    int bid = blockIdx.x;
    int tid = threadIdx.x;

    if (bid < 32) {
        __shared__ float s_wf[256][17];   // wf_w[:, k0:k0+16], pad vs bank conflicts
        __shared__ float s_aw[DD];
        __shared__ float s_part[16][17];
        int k0 = bid * 16;

        {   // stage the 16-column wf_w slice (one 64B row-chunk per thread)
            const float* wr = wf_w + (size_t)tid * TWO_D + k0;
#pragma unroll
            for (int j = 0; j < 16; ++j) s_wf[tid][j] = wr[j];
        }
        s_aw[tid] = aw[tid];
        __syncthreads();

        int kl = tid >> 4, ng = tid & 15;   // k-row local, n-group (16 cols)
        float4 acc[4];
#pragma unroll
        for (int c = 0; c < 4; ++c) acc[c] = (float4){0.f, 0.f, 0.f, 0.f};
        const float4* w24 = (const float4*)at_w2;
#pragma unroll 4
        for (int d = 0; d < DD; ++d) {
            float wfv = s_wf[d][kl];
            const float4* rowp = w24 + d * 64 + ng * 4;
#pragma unroll
            for (int c = 0; c < 4; ++c) {
                float4 w2 = rowp[c];
                acc[c].x += wfv * w2.x; acc[c].y += wfv * w2.y;
                acc[c].z += wfv * w2.z; acc[c].w += wfv * w2.w;
            }
        }
        float* wco = Wc + (size_t)(k0 + kl) * DD + ng * 16;
#pragma unroll
        for (int c = 0; c < 4; ++c) *(float4*)(wco + c * 4) = acc[c];

        // v[k0+kl] = dot(wf_w[:,k0+kl], aw): 16-elem partial per thread
        float p = 0.f;
#pragma unroll
        for (int j = 0; j < 16; ++j) p += s_wf[ng * 16 + j][kl] * s_aw[ng * 16 + j];
        s_part[kl][ng] = p;
        __syncthreads();
        if (tid < 16) {
            float s = 0.f;
#pragma unroll
            for (int j = 0; j < 16; ++j) s += s_part[tid][j];
            v[k0 + tid] = s;
        }
    } else if (bid < 96) {
        // transpose 4 columns of at_w1: w1t[t][k0+j] = at_w1[k0+j][t]
        __shared__ ushort s_t[4][DD];
        int k0 = (bid - 32) * 4;
#pragma unroll
        for (int j = 0; j < 4; ++j)
            s_t[j][tid] = f2bf(at_w1[(k0 + j) * DD + tid]);
        __syncthreads();
        ushort4 pk;
        pk.x = s_t[0][tid]; pk.y = s_t[1][tid];
        pk.z = s_t[2][tid]; pk.w = s_t[3][tid];
        *(ushort4*)(w1t + (size_t)tid * DD + k0) = pk;
    } else if (bid == 96) {
        __shared__ float s_wb[DD];
        __shared__ float wred[4];
        s_wb[tid] = wf_b[tid];
        float awv = aw[tid];
        __syncthreads();
        float accb = 0.f;
#pragma unroll 8
        for (int d = 0; d < DD; ++d) accb += s_wb[d] * at_w2[d * DD + tid];
        bc[tid] = at_bias[tid] + accb;
        float s2 = s_wb[tid] * awv;
        s2 = wave_sum64(s2);
        if ((tid & 63) == 0) wred[tid >> 6] = s2;
        __syncthreads();
        if (tid == 0) c0[0] = wred[0] + wred[1] + wred[2] + wred[3] + ab[0];
    } else if (bid < 297) {
        int i = (bid - 97) * 256 + tid;
        flags[items[i]] = 1;
    } else {
        // 8 independent float4 loads per thread (MLP), coalesced per step
        int base4 = (bid - 297) * (256 * 8) + tid;   // float4 index
        float4 val[8];
#pragma unroll
        for (int j = 0; j < 8; ++j)
            val[j] = *(const float4*)(emb + (size_t)(base4 + j * 256) * 4);
#pragma unroll
        for (int j = 0; j < 8; ++j) {
            ushort4 o;
            o.x = f2bf(val[j].x); o.y = f2bf(val[j].y);
            o.z = f2bf(val[j].z); o.w = f2bf(val[j].w);
            *(ushort4*)(ebf + (size_t)(base4 + j * 256) * 4) = o;
        }
    }
}

// ---------------- L2: t2 (16-row blocks) + alpha | conv (bf16 table) --------
// t2a: 256 blocks, 16 b-rows x 64 n-cols each; each wave computes 4 rows per
// Wc element -> Wc logical traffic 32 MB (was 128 MB). Same sequential-k fp32
// accumulation as before (bit-identical t2).
// bid [256,10256): per-node conv from bf16 ebf (one wave per node).
__global__ __launch_bounds__(256) void k_stage2(
    const ushort* __restrict__ ebf, const int* __restrict__ adj_cols,
    const float* __restrict__ adj_vals, const int* __restrict__ flags,
    ushort* __restrict__ gbf,
    const float* __restrict__ tgt, const float* __restrict__ Wc,
    const float* __restrict__ bc, const float* __restrict__ v,
    const float* __restrict__ c0, float* __restrict__ t2,
    float* __restrict__ alpha)
{
    int bid = blockIdx.x;
    int tid = threadIdx.x;
    int wv = tid >> 6, lane = tid & 63;

    if (bid < 256) {
        __shared__ float x_s[16 * TWO_D];   // 32 KB
        int btile = bid >> 2, ntile = bid & 3;
        int b0 = btile * 16, n0 = ntile * 64;
        for (int i = tid; i < 16 * TWO_D; i += 256)
            x_s[i] = tgt[(size_t)b0 * TWO_D + i];
        __syncthreads();

        int r0 = wv * 4;
        const float* x0 = x_s + (r0 + 0) * TWO_D;
        const float* x1 = x_s + (r0 + 1) * TWO_D;
        const float* x2 = x_s + (r0 + 2) * TWO_D;
        const float* x3 = x_s + (r0 + 3) * TWO_D;
        float bb = bc[n0 + lane];
        float a0 = bb, a1 = bb, a2 = bb, a3 = bb;
#pragma unroll 8
        for (int k = 0; k < TWO_D; ++k) {
            float wc = Wc[(size_t)k * DD + n0 + lane];
            a0 += x0[k] * wc; a1 += x1[k] * wc;
            a2 += x2[k] * wc; a3 += x3[k] * wc;
        }
        t2[(size_t)(b0 + r0 + 0) * DD + n0 + lane] = a0;
        t2[(size_t)(b0 + r0 + 1) * DD + n0 + lane] = a1;
        t2[(size_t)(b0 + r0 + 2) * DD + n0 + lane] = a2;
        t2[(size_t)(b0 + r0 + 3) * DD + n0 + lane] = a3;

        if (ntile == 0) {
            float vr[8];
#pragma unroll
            for (int i = 0; i < 8; ++i) vr[i] = v[lane + 64 * i];
#pragma unroll
            for (int r = 0; r < 4; ++r) {
                const float* xr = x_s + (r0 + r) * TWO_D;
                float s = 0.f;
#pragma unroll
                for (int i = 0; i < 8; ++i) s += xr[lane + 64 * i] * vr[i];
                s = wave_sum64(s);
                if (lane == 0) {
                    float a = 1.f + 1.f / (1.f + expf(-(s + c0[0])));
                    if (a == 1.f) a = 1.00001f;
                    alpha[b0 + r0 + r] = a;
                }
            }
        }
    } else {
        int n = (bid - 256) * 4 + wv;
        if (flags[n] != 1) return;
        int colv = 0; float valv = 0.f;
        if (lane < DEG) { colv = adj_cols[n * DEG + lane]; valv = adj_vals[n * DEG + lane]; }
        int cols[DEG]; float vals[DEG];
#pragma unroll
        for (int k = 0; k < DEG; ++k) {
            cols[k] = __builtin_amdgcn_readlane(colv, k);
            vals[k] = __int_as_float(__builtin_amdgcn_readlane(__float_as_int(valv), k));
        }
        ushort4 s = *(const ushort4*)(ebf + (size_t)n * DD + lane * 4);
        ushort4 e[DEG];
#pragma unroll
        for (int k = 0; k < DEG; ++k)
            e[k] = *(const ushort4*)(ebf + (size_t)cols[k] * DD + lane * 4);
        float a0 = bf2f(s.x), a1 = bf2f(s.y), a2 = bf2f(s.z), a3 = bf2f(s.w);
#pragma unroll
        for (int k = 0; k < DEG; ++k) {
            float vv = vals[k];
            a0 += vv * bf2f(e[k].x); a1 += vv * bf2f(e[k].y);
            a2 += vv * bf2f(e[k].z); a3 += vv * bf2f(e[k].w);
        }
        ushort4 o;
        o.x = f2bf(0.5f * a0); o.y = f2bf(0.5f * a1);
        o.z = f2bf(0.5f * a2); o.w = f2bf(0.5f * a3);
        *(ushort4*)(gbf + (size_t)n * DD + lane * 4) = o;
    }
}

__device__ __forceinline__ float pw(float z, float invv) {
    return hw_exp2(invv * hw_log2(z));   // z=0 -> exp2(-inf)=0, correct limit
}

// ---------------- L3 fused: no-LDS MFMA + redundant-per-wave entmax ---------
// r2-proven structure (42.0 us, 0 bank conflicts, 60 VGPR). Changes: full
// unroll of the (kc,ks) load/MFMA loop so the scheduler can keep multiple
// 8-load bursts in flight within the 128-VGPR budget; alpha/at_w0 hoisted
// off the serial tail.
__global__ __launch_bounds__(256, 4) void k_fused(
    const int* __restrict__ items, const ushort* __restrict__ gbf,
    const ushort* __restrict__ w1t, const float* __restrict__ t2,
    const float* __restrict__ at_w0, const float* __restrict__ alpha,
    float* __restrict__ out)
{
    __shared__ float t2_s[DD];
    __shared__ float sred[64][4];
    __shared__ int s_items[64];
    __shared__ float red[4];

    int b = blockIdx.x;
    int tid = threadIdx.x;
    int lane = tid & 63, wv = tid >> 6;
    int cn = lane & 15, q = lane >> 4;
    int n0 = wv * 64;

    float a = alpha[b];                    // hoisted scalar (SGPR path)
    float w0v[4];
#pragma unroll
    for (int nt = 0; nt < 4; ++nt) w0v[nt] = at_w0[n0 + nt * 16 + cn];

    if (tid < 64) {
        int l = (tid < LL) ? tid : 0;      // pad rows duplicate row 0
        s_items[tid] = items[b * LL + l];
    }
    t2_s[tid] = t2[b * DD + tid];
    __syncthreads();

    // A rows: hidden rows mt*16+cn (gathered); B rows: w1t rows n0+nt*16+cn
    const ushort* arow[4];
#pragma unroll
    for (int mt = 0; mt < 4; ++mt)
        arow[mt] = gbf + (size_t)s_items[mt * 16 + cn] * DD;
    const ushort* brow[4];
#pragma unroll
    for (int nt = 0; nt < 4; ++nt)
        brow[nt] = w1t + (size_t)(n0 + nt * 16 + cn) * DD;

    floatx4 acc[4][4];
#pragma unroll
    for (int mt = 0; mt < 4; ++mt)
#pragma unroll
        for (int nt = 0; nt < 4; ++nt)
            acc[mt][nt] = (floatx4){0.f, 0.f, 0.f, 0.f};

#pragma unroll
    for (int kc = 0; kc < 4; ++kc) {
#pragma unroll
        for (int ks = 0; ks < 2; ++ks) {
            int ko = kc * 64 + ks * 32 + q * 8;
            short8 af[4], bfr[4];
#pragma unroll
            for (int mt = 0; mt < 4; ++mt)
                af[mt] = *(const short8*)(arow[mt] + ko);
#pragma unroll
            for (int nt = 0; nt < 4; ++nt)
                bfr[nt] = *(const short8*)(brow[nt] + ko);
#pragma unroll
            for (int mt = 0; mt < 4; ++mt)
#pragma unroll
                for (int nt = 0; nt < 4; ++nt)
                    acc[mt][nt] = __builtin_amdgcn_mfma_f32_16x16x32_bf16(
                        af[mt], bfr[nt], acc[mt][nt], 0, 0, 0);
        }
    }

    // epilogue: relu(acc + t2) @ w0, reduce 16 cols per lane-group
#pragma unroll
    for (int mt = 0; mt < 4; ++mt) {
#pragma unroll
        for (int r = 0; r < 4; ++r) {
            int row = mt * 16 + q * 4 + r;
            float p = 0.f;
#pragma unroll
            for (int nt = 0; nt < 4; ++nt) {
                int col = n0 + nt * 16 + cn;
                float vvv = acc[mt][nt][r] + t2_s[col];
                p += fmaxf(vvv, 0.f) * w0v[nt];
            }
            p += __shfl_xor(p, 1, 64);
            p += __shfl_xor(p, 2, 64);
            p += __shfl_xor(p, 4, 64);
            p += __shfl_xor(p, 8, 64);
            if (cn == 0) sred[row][wv] = p;
        }
    }
    __syncthreads();

    // per-wave redundant score fold + entmax bisect (DPP sums, VALU chain)
    float sc = sred[lane][0] + sred[lane][1] + sred[lane][2] + sred[lane][3];

    float am1 = a - 1.f;
    float invv = 1.f / am1;
    float x = (lane < LL) ? sc : -__builtin_inff();
    float Xa = x * am1;

    float mx = wave_max64(Xa);
    float tau_lo = mx - 1.f;
    float tau_hi = mx - hw_exp2(am1 * hw_log2(1.f / (float)LL));

    float f_lo = dpp_sum64(pw(fmaxf(Xa - tau_lo, 0.f), invv)) - 1.f;

    float dm = tau_hi - tau_lo;
    float tau_m = tau_lo;
#pragma unroll 1
    for (int it = 0; it < NITER; ++it) {
        dm *= 0.5f;
        tau_m = tau_lo + dm;
        // exact early-exit: once dm rounds away, every remaining
        // iteration is a no-op (rounding monotonicity) -> identical result
        if (tau_m == tau_lo) break;
        float f_m = dpp_sum64(pw(fmaxf(Xa - tau_m, 0.f), invv)) - 1.f;
        if (f_m * f_lo >= 0.f) tau_lo = tau_m;
    }
    float pm = pw(fmaxf(Xa - tau_m, 0.f), invv);
    float sden = dpp_sum64(pm);
    float pmn = pm / sden;                     // lane l holds attn[l]

    // weighted sum: thread d = tid, attn broadcast via readlane (own wave)
    int d = tid;
    float c = 0.f;
#pragma unroll
    for (int l = 0; l < LL; ++l) {
        float al = __int_as_float(__builtin_amdgcn_readlane(__float_as_int(pmn), l));
        c += al * bf2f(gbf[(size_t)s_items[l] * DD + d]);
    }

    const float SC = 1.0507009873554805f;
    const float AL = 1.6732632423543772f;
    c = SC * (c > 0.f ? c : AL * expm1f(c));

    float ss = wave_sum64(c * c);
    if (lane == 0) red[wv] = ss;
    __syncthreads();
    float tot = red[0] + red[1] + red[2] + red[3];
    out[b * DD + d] = c / sqrtf(tot);
}

extern "C" void kernel_launch(void* const* d_in, const int* in_sizes, int n_in,
                              void* d_out, int out_size, void* d_ws, size_t ws_size,
                              hipStream_t stream) {
    const int*   items     = (const int*)  d_in[0];
    const float* tgt       = (const float*)d_in[3];
    const float* item_emb  = (const float*)d_in[4];
    const int*   adj_cols  = (const int*)  d_in[6];
    const float* adj_vals  = (const float*)d_in[7];
    const float* wf_w      = (const float*)d_in[8];
    const float* wf_b      = (const float*)d_in[9];
    const float* alphaw_w  = (const float*)d_in[10];
    const float* alphaw_b  = (const float*)d_in[11];
    const float* at_w0     = (const float*)d_in[12];
    const float* at_w1     = (const float*)d_in[13];
    const float* at_w2     = (const float*)d_in[14];
    const float* at_bias   = (const float*)d_in[15];

    const size_t SZ_TAB = (size_t)NN * DD * sizeof(ushort);      // 20.48 MB
    char* ws = (char*)d_ws;
    ushort* gbf = (ushort*)ws;   ws += SZ_TAB;
    ushort* ebf = (ushort*)ws;   ws += SZ_TAB;
    ushort* w1t = (ushort*)ws;   ws += (size_t)DD * DD * sizeof(ushort);
    int*   flags = (int*)ws;     ws += (size_t)NN * sizeof(int);
    float* Wc     = (float*)ws;  ws += (size_t)TWO_D * DD * sizeof(float);
    float* bcv    = (float*)ws;  ws += (size_t)DD * sizeof(float);
    float* vv     = (float*)ws;  ws += (size_t)TWO_D * sizeof(float);
    float* c0v    = (float*)ws;  ws += 16 * sizeof(float);
    float* t2     = (float*)ws;  ws += (size_t)BB * DD * sizeof(float);
    float* alpha  = (float*)ws;  ws += ((size_t)BB + 32) * sizeof(float);
    float* out    = (float*)d_out;

    k_stage1<<<1547, 256, 0, stream>>>(item_emb, ebf, items, flags,
                                       wf_w, wf_b, at_w2, at_bias,
                                       alphaw_w, alphaw_b, at_w1,
                                       Wc, vv, bcv, c0v, w1t);
    k_stage2<<<10256, 256, 0, stream>>>(ebf, adj_cols, adj_vals, flags, gbf,
                                        tgt, Wc, bcv, vv, c0v, t2, alpha);
    k_fused<<<BB, 256, 0, stream>>>(items, gbf, w1t, t2, at_w0, alpha, out);
}

// Round 6
// 191.193 us; speedup vs baseline: 1.2758x; 1.2758x over previous
//
#include <hip/hip_runtime.h>
#include <hip/hip_bf16.h>
#include <math.h>

#define BB 1024     // batch
#define LL 50       // sequence length
#define DD 256      // embedding dim
#define TWO_D 512
#define NN 40000    // nodes
#define DEG 12      // neighbors per node (adj_rows = repeat(arange(N), DEG))
#define NITER 50    // entmax bisect iterations

typedef __attribute__((ext_vector_type(8))) short short8;
typedef __attribute__((ext_vector_type(4))) float floatx4;

__device__ __forceinline__ float wave_sum64(float v) {
#pragma unroll
    for (int off = 32; off > 0; off >>= 1) v += __shfl_xor(v, off, 64);
    return v;
}
__device__ __forceinline__ float wave_max64(float v) {
#pragma unroll
    for (int off = 32; off > 0; off >>= 1) v = fmaxf(v, __shfl_xor(v, off, 64));
    return v;
}
// Full-wave sum via DPP (canonical GCN sequence), result uniform via readlane.
__device__ __forceinline__ float dpp_sum64(float v) {
#define DPPADD(ctrl, rm, bm) \
    v += __int_as_float(__builtin_amdgcn_update_dpp(0, __float_as_int(v), ctrl, rm, bm, true))
    DPPADD(0x111, 0xF, 0xF);   // row_shr:1
    DPPADD(0x112, 0xF, 0xF);   // row_shr:2
    DPPADD(0x114, 0xF, 0xE);   // row_shr:4
    DPPADD(0x118, 0xF, 0xC);   // row_shr:8
    DPPADD(0x142, 0xA, 0xF);   // row_bcast:15
    DPPADD(0x143, 0xC, 0xF);   // row_bcast:31  -> lane63 = full sum
#undef DPPADD
    return __int_as_float(__builtin_amdgcn_readlane(__float_as_int(v), 63));
}
__device__ __forceinline__ float bf2f(ushort u) {
    union { unsigned int i; float f; } c; c.i = ((unsigned int)u) << 16; return c.f;
}
__device__ __forceinline__ ushort f2bf(float f) {
    __hip_bfloat16 h = __float2bfloat16(f);
    return *(ushort*)&h;
}
__device__ __forceinline__ float hw_exp2(float x) { return __builtin_amdgcn_exp2f(x); }
__device__ __forceinline__ float hw_log2(float x) { return __builtin_amdgcn_logf(x); }

// ---------------- L1: wprep (tiled, 512-way parallel) | mark | emb->bf16 ----
// Restored r1/r2 structure: 512 blocks each own one k; at_w2 logical re-reads
// are L2-hits (256 KB table, per-XCD replicated) — parallelism is the scarce
// resource here, not logical traffic (r5 lesson: 32-block version = 70 us at
// 1% VALU).
__global__ __launch_bounds__(256) void k_stage1(
    const float* __restrict__ emb, ushort* __restrict__ ebf,
    const int* __restrict__ items, int* __restrict__ flags,
    const float* __restrict__ wf_w, const float* __restrict__ wf_b,
    const float* __restrict__ at_w2, const float* __restrict__ at_bias,
    const float* __restrict__ aw, const float* __restrict__ ab,
    const float* __restrict__ at_w1,
    float* __restrict__ Wc, float* __restrict__ v,
    float* __restrict__ bc, float* __restrict__ c0,
    ushort* __restrict__ w1t)
{
    __shared__ float wcol[DD];
    __shared__ float4 s_p[4][64];
    __shared__ float wred[4];
    __shared__ ushort s_t[4][DD];
    int bid = blockIdx.x;
    int tid = threadIdx.x;

    if (bid < 512) {
        int k = bid;
        int lane = tid & 63, wv = tid >> 6;
        int ng = tid & 63;      // n-group: n = ng*4 .. ng*4+3
        int dq = tid >> 6;      // d-quarter

        wcol[tid] = wf_w[tid * TWO_D + k];
        __syncthreads();

        // 64 d-iterations per thread, float4 across n (coalesced), MLP depth 8
        float4 acc = {0.f, 0.f, 0.f, 0.f};
        const float4* w24 = (const float4*)at_w2;
#pragma unroll 8
        for (int d = dq * 64; d < dq * 64 + 64; ++d) {
            float4 w2 = w24[d * 64 + ng];
            float wc = wcol[d];
            acc.x += wc * w2.x; acc.y += wc * w2.y;
            acc.z += wc * w2.z; acc.w += wc * w2.w;
        }
        s_p[dq][ng] = acc;

        // v[k] while the reduction data settles
        float s1 = wcol[tid] * aw[tid];
        s1 = wave_sum64(s1);
        if (lane == 0) wred[wv] = s1;
        __syncthreads();
        if (tid == 0) v[k] = wred[0] + wred[1] + wred[2] + wred[3];

        if (tid < 64) {
            float4 r0 = s_p[0][tid], r1 = s_p[1][tid];
            float4 r2 = s_p[2][tid], r3 = s_p[3][tid];
            float4 rr;
            rr.x = (r0.x + r1.x) + (r2.x + r3.x);
            rr.y = (r0.y + r1.y) + (r2.y + r3.y);
            rr.z = (r0.z + r1.z) + (r2.z + r3.z);
            rr.w = (r0.w + r1.w) + (r2.w + r3.w);
            *(float4*)(Wc + k * DD + tid * 4) = rr;
        }

        if (k < 64) {
            // transpose 4 columns of at_w1: w1t[t][k0+j] = at_w1[k0+j][t]
            int k0 = k * 4;
#pragma unroll
            for (int j = 0; j < 4; ++j)
                s_t[j][tid] = f2bf(at_w1[(k0 + j) * DD + tid]);
            __syncthreads();
            ushort4 pk;
            pk.x = s_t[0][tid]; pk.y = s_t[1][tid];
            pk.z = s_t[2][tid]; pk.w = s_t[3][tid];
            *(ushort4*)(w1t + tid * DD + k0) = pk;
        }

        if (k == 0) {
            __syncthreads();
            wcol[tid] = wf_b[tid];
            __syncthreads();
            float b[8];
#pragma unroll
            for (int j = 0; j < 8; ++j) b[j] = 0.f;
#pragma unroll 4
            for (int d = 0; d < DD; d += 8) {
#pragma unroll
                for (int j = 0; j < 8; ++j)
                    b[j] += wcol[d + j] * at_w2[(d + j) * DD + tid];
            }
            bc[tid] = at_bias[tid] + ((b[0] + b[1]) + (b[2] + b[3]))
                                   + ((b[4] + b[5]) + (b[6] + b[7]));
            float s2 = wcol[tid] * aw[tid];
            s2 = wave_sum64(s2);
            if (lane == 0) wred[wv] = s2;
            __syncthreads();
            if (tid == 0) c0[0] = wred[0] + wred[1] + wred[2] + wred[3] + ab[0];
        }
    } else if (bid < 712) {
        int i = (bid - 512) * 256 + tid;
        flags[items[i]] = 1;
    } else {
        // 8 independent float4 loads per thread (MLP), coalesced per step
        int base4 = (bid - 712) * (256 * 8) + tid;   // float4 index
        float4 val[8];
#pragma unroll
        for (int j = 0; j < 8; ++j)
            val[j] = *(const float4*)(emb + (size_t)(base4 + j * 256) * 4);
#pragma unroll
        for (int j = 0; j < 8; ++j) {
            ushort4 o;
            o.x = f2bf(val[j].x); o.y = f2bf(val[j].y);
            o.z = f2bf(val[j].z); o.w = f2bf(val[j].w);
            *(ushort4*)(ebf + (size_t)(base4 + j * 256) * 4) = o;
        }
    }
}

// ---------------- L2: t2 direct + alpha | conv (bf16 table) -----------------
// Restored r1/r2 structure: 1024 t2 blocks (4 b-rows each) launched FIRST so
// the long GEMV overlaps the conv blocks; conv = one wave per node.
__global__ __launch_bounds__(256) void k_stage2(
    const ushort* __restrict__ ebf, const int* __restrict__ adj_cols,
    const float* __restrict__ adj_vals, const int* __restrict__ flags,
    ushort* __restrict__ gbf,
    const float* __restrict__ tgt, const float* __restrict__ Wc,
    const float* __restrict__ bc, const float* __restrict__ v,
    const float* __restrict__ c0, float* __restrict__ t2,
    float* __restrict__ alpha)
{
    __shared__ float x_s[4 * TWO_D];
    int bid = blockIdx.x;
    int tid = threadIdx.x;
    int wv = tid >> 6, lane = tid & 63;

    if (bid < 1024) {
        int t = bid;
        int btile = t >> 2, ntile = t & 3;
        int b0 = btile * 4, n0 = ntile * 64;
        int j = wv;
        for (int i = tid; i < 4 * TWO_D; i += 256) x_s[i] = tgt[b0 * TWO_D + i];
        __syncthreads();

        float acc = bc[n0 + lane];
        const float* xr = x_s + j * TWO_D;
#pragma unroll 8
        for (int k = 0; k < TWO_D; ++k)
            acc += xr[k] * Wc[k * DD + n0 + lane];
        t2[(b0 + j) * DD + n0 + lane] = acc;

        if (ntile == 0) {
            float s = 0.f;
#pragma unroll
            for (int i = 0; i < 8; ++i) s += xr[lane + 64 * i] * v[lane + 64 * i];
            s = wave_sum64(s);
            if (lane == 0) {
                float a = 1.f + 1.f / (1.f + expf(-(s + c0[0])));
                if (a == 1.f) a = 1.00001f;
                alpha[b0 + j] = a;
            }
        }
    } else {
        int n = (bid - 1024) * 4 + wv;
        if (flags[n] != 1) return;
        int colv = 0; float valv = 0.f;
        if (lane < DEG) { colv = adj_cols[n * DEG + lane]; valv = adj_vals[n * DEG + lane]; }
        int cols[DEG]; float vals[DEG];
#pragma unroll
        for (int k = 0; k < DEG; ++k) {
            cols[k] = __builtin_amdgcn_readlane(colv, k);
            vals[k] = __int_as_float(__builtin_amdgcn_readlane(__float_as_int(valv), k));
        }
        ushort4 s = *(const ushort4*)(ebf + (size_t)n * DD + lane * 4);
        ushort4 e[DEG];
#pragma unroll
        for (int k = 0; k < DEG; ++k)
            e[k] = *(const ushort4*)(ebf + (size_t)cols[k] * DD + lane * 4);
        float a0 = bf2f(s.x), a1 = bf2f(s.y), a2 = bf2f(s.z), a3 = bf2f(s.w);
#pragma unroll
        for (int k = 0; k < DEG; ++k) {
            float vv = vals[k];
            a0 += vv * bf2f(e[k].x); a1 += vv * bf2f(e[k].y);
            a2 += vv * bf2f(e[k].z); a3 += vv * bf2f(e[k].w);
        }
        ushort4 o;
        o.x = f2bf(0.5f * a0); o.y = f2bf(0.5f * a1);
        o.z = f2bf(0.5f * a2); o.w = f2bf(0.5f * a3);
        *(ushort4*)(gbf + (size_t)n * DD + lane * 4) = o;
    }
}

__device__ __forceinline__ float pw(float z, float invv) {
    return hw_exp2(invv * hw_log2(z));   // z=0 -> exp2(-inf)=0, correct limit
}

// ---------------- L3 fused: no-LDS MFMA + redundant-per-wave entmax ---------
// Restored r2 version verbatim (42.0 us measured, 0 bank conflicts, 60 VGPR,
// 36% occupancy — best-measured fused variant).
__global__ __launch_bounds__(256, 4) void k_fused(
    const int* __restrict__ items, const ushort* __restrict__ gbf,
    const ushort* __restrict__ w1t, const float* __restrict__ t2,
    const float* __restrict__ at_w0, const float* __restrict__ alpha,
    float* __restrict__ out)
{
    __shared__ float t2_s[DD];
    __shared__ float sred[64][4];
    __shared__ int s_items[64];
    __shared__ float red[4];

    int b = blockIdx.x;
    int tid = threadIdx.x;
    int lane = tid & 63, wv = tid >> 6;
    int cn = lane & 15, q = lane >> 4;
    int n0 = wv * 64;

    if (tid < 64) {
        int l = (tid < LL) ? tid : 0;          // pad rows duplicate row 0
        s_items[tid] = items[b * LL + l];
    }
    t2_s[tid] = t2[b * DD + tid];
    __syncthreads();

    // A rows: hidden rows mt*16+cn (gathered); B rows: w1t rows n0+nt*16+cn
    const ushort* arow[4];
#pragma unroll
    for (int mt = 0; mt < 4; ++mt)
        arow[mt] = gbf + (size_t)s_items[mt * 16 + cn] * DD;
    const ushort* brow[4];
#pragma unroll
    for (int nt = 0; nt < 4; ++nt)
        brow[nt] = w1t + (size_t)(n0 + nt * 16 + cn) * DD;

    floatx4 acc[4][4];
#pragma unroll
    for (int mt = 0; mt < 4; ++mt)
#pragma unroll
        for (int nt = 0; nt < 4; ++nt)
            acc[mt][nt] = (floatx4){0.f, 0.f, 0.f, 0.f};

#pragma unroll 1
    for (int kc = 0; kc < 4; ++kc) {
#pragma unroll
        for (int ks = 0; ks < 2; ++ks) {
            int ko = kc * 64 + ks * 32 + q * 8;
            short8 af[4], bfr[4];
#pragma unroll
            for (int mt = 0; mt < 4; ++mt)
                af[mt] = *(const short8*)(arow[mt] + ko);
#pragma unroll
            for (int nt = 0; nt < 4; ++nt)
                bfr[nt] = *(const short8*)(brow[nt] + ko);
#pragma unroll
            for (int mt = 0; mt < 4; ++mt)
#pragma unroll
                for (int nt = 0; nt < 4; ++nt)
                    acc[mt][nt] = __builtin_amdgcn_mfma_f32_16x16x32_bf16(
                        af[mt], bfr[nt], acc[mt][nt], 0, 0, 0);
        }
    }

    // epilogue: relu(acc + t2) @ w0, reduce 16 cols per lane-group
    float w0v[4];
#pragma unroll
    for (int nt = 0; nt < 4; ++nt) w0v[nt] = at_w0[n0 + nt * 16 + cn];
#pragma unroll
    for (int mt = 0; mt < 4; ++mt) {
#pragma unroll
        for (int r = 0; r < 4; ++r) {
            int row = mt * 16 + q * 4 + r;
            float p = 0.f;
#pragma unroll
            for (int nt = 0; nt < 4; ++nt) {
                int col = n0 + nt * 16 + cn;
                float vvv = acc[mt][nt][r] + t2_s[col];
                p += fmaxf(vvv, 0.f) * w0v[nt];
            }
            p += __shfl_xor(p, 1, 64);
            p += __shfl_xor(p, 2, 64);
            p += __shfl_xor(p, 4, 64);
            p += __shfl_xor(p, 8, 64);
            if (cn == 0) sred[row][wv] = p;
        }
    }
    __syncthreads();

    // per-wave redundant score fold + entmax bisect (DPP sums, VALU chain)
    float sc = sred[lane][0] + sred[lane][1] + sred[lane][2] + sred[lane][3];

    float a = alpha[b];
    float am1 = a - 1.f;
    float invv = 1.f / am1;
    float x = (lane < LL) ? sc : -__builtin_inff();
    float Xa = x * am1;

    float mx = wave_max64(Xa);
    float tau_lo = mx - 1.f;
    float tau_hi = mx - hw_exp2(am1 * hw_log2(1.f / (float)LL));

    float f_lo = dpp_sum64(pw(fmaxf(Xa - tau_lo, 0.f), invv)) - 1.f;

    float dm = tau_hi - tau_lo;
    float tau_m = tau_lo;
#pragma unroll 1
    for (int it = 0; it < NITER; ++it) {
        dm *= 0.5f;
        tau_m = tau_lo + dm;
        // exact early-exit: once dm rounds away, every remaining
        // iteration is a no-op (rounding monotonicity) -> identical result
        if (tau_m == tau_lo) break;
        float f_m = dpp_sum64(pw(fmaxf(Xa - tau_m, 0.f), invv)) - 1.f;
        if (f_m * f_lo >= 0.f) tau_lo = tau_m;
    }
    float pm = pw(fmaxf(Xa - tau_m, 0.f), invv);
    float sden = dpp_sum64(pm);
    float pmn = pm / sden;                     // lane l holds attn[l]

    // weighted sum: thread d = tid, attn broadcast via readlane (own wave)
    int d = tid;
    float c = 0.f;
#pragma unroll
    for (int l = 0; l < LL; ++l) {
        float al = __int_as_float(__builtin_amdgcn_readlane(__float_as_int(pmn), l));
        c += al * bf2f(gbf[(size_t)s_items[l] * DD + d]);
    }

    const float SC = 1.0507009873554805f;
    const float AL = 1.6732632423543772f;
    c = SC * (c > 0.f ? c : AL * expm1f(c));

    float ss = wave_sum64(c * c);
    if (lane == 0) red[wv] = ss;
    __syncthreads();
    float tot = red[0] + red[1] + red[2] + red[3];
    out[b * DD + d] = c / sqrtf(tot);
}

extern "C" void kernel_launch(void* const* d_in, const int* in_sizes, int n_in,
                              void* d_out, int out_size, void* d_ws, size_t ws_size,
                              hipStream_t stream) {
    const int*   items     = (const int*)  d_in[0];
    const float* tgt       = (const float*)d_in[3];
    const float* item_emb  = (const float*)d_in[4];
    const int*   adj_cols  = (const int*)  d_in[6];
    const float* adj_vals  = (const float*)d_in[7];
    const float* wf_w      = (const float*)d_in[8];
    const float* wf_b      = (const float*)d_in[9];
    const float* alphaw_w  = (const float*)d_in[10];
    const float* alphaw_b  = (const float*)d_in[11];
    const float* at_w0     = (const float*)d_in[12];
    const float* at_w1     = (const float*)d_in[13];
    const float* at_w2     = (const float*)d_in[14];
    const float* at_bias   = (const float*)d_in[15];

    const size_t SZ_TAB = (size_t)NN * DD * sizeof(ushort);      // 20.48 MB
    char* ws = (char*)d_ws;
    ushort* gbf = (ushort*)ws;   ws += SZ_TAB;
    ushort* ebf = (ushort*)ws;   ws += SZ_TAB;
    ushort* w1t = (ushort*)ws;   ws += (size_t)DD * DD * sizeof(ushort);
    int*   flags = (int*)ws;     ws += (size_t)NN * sizeof(int);
    float* Wc     = (float*)ws;  ws += (size_t)TWO_D * DD * sizeof(float);
    float* bcv    = (float*)ws;  ws += (size_t)DD * sizeof(float);
    float* vv     = (float*)ws;  ws += (size_t)TWO_D * sizeof(float);
    float* c0v    = (float*)ws;  ws += 16 * sizeof(float);
    float* t2     = (float*)ws;  ws += (size_t)BB * DD * sizeof(float);
    float* alpha  = (float*)ws;  ws += ((size_t)BB + 32) * sizeof(float);
    float* out    = (float*)d_out;

    k_stage1<<<1962, 256, 0, stream>>>(item_emb, ebf, items, flags,
                                       wf_w, wf_b, at_w2, at_bias,
                                       alphaw_w, alphaw_b, at_w1,
                                       Wc, vv, bcv, c0v, w1t);
    k_stage2<<<11024, 256, 0, stream>>>(ebf, adj_cols, adj_vals, flags, gbf,
                                        tgt, Wc, bcv, vv, c0v, t2, alpha);
    k_fused<<<BB, 256, 0, stream>>>(items, gbf, w1t, t2, at_w0, alpha, out);
}